// Round 13
// baseline (1469.721 us; speedup 1.0000x reference)
//
#include <hip/hip_runtime.h>
#include <hip/hip_bf16.h>
#include <math.h>

#define DEVI __device__ __forceinline__

static constexpr int BB = 32, NN = 2048, S1 = 512, S2 = 128;

typedef float f32x4 __attribute__((ext_vector_type(4)));
typedef short s16x8 __attribute__((ext_vector_type(8)));

// ---------------- static workspace layout (float units) ----------------
static constexpr size_t OFF_XS   = 0;
static constexpr size_t OFF_YS   = OFF_XS + (size_t)BB*NN;
static constexpr size_t OFF_ZS   = OFF_YS + (size_t)BB*NN;
static constexpr size_t OFF_SSQ  = OFF_ZS + (size_t)BB*NN;
static constexpr size_t OFF_NX1X = OFF_SSQ + (size_t)BB*NN;
static constexpr size_t OFF_NX1Y = OFF_NX1X + (size_t)BB*S1;
static constexpr size_t OFF_NX1Z = OFF_NX1Y + (size_t)BB*S1;
static constexpr size_t OFF_NX2X = OFF_NX1Z + (size_t)BB*S1;
static constexpr size_t OFF_NX2Y = OFF_NX2X + (size_t)BB*S2;
static constexpr size_t OFF_NX2Z = OFF_NX2Y + (size_t)BB*S2;
static constexpr size_t OFF_CODE = OFF_NX2Z + (size_t)BB*S2;          // (unused after R13)
static constexpr size_t OFF_O3P  = OFF_CODE + (size_t)3*BB*512;
static constexpr size_t OFF_P1   = OFF_O3P + (size_t)3*BB*4*512;
static constexpr size_t OFF_X3   = OFF_P1 + (size_t)3*BB*S1*128;      // (unused)
static constexpr size_t OFF_H3   = OFF_X3 + (size_t)3*BB*S2*260;     // (unused)
static constexpr size_t OFF_W    = OFF_H3 + (size_t)3*BB*S2*512;
static constexpr size_t W1A  = OFF_W;
static constexpr size_t B1A  = W1A + 3*64*6;
static constexpr size_t W2A  = B1A + 3*64;
static constexpr size_t B2A  = W2A + 3*128*64;
static constexpr size_t W1B  = B2A + 3*128;
static constexpr size_t B1B  = W1B + 3*128*132;
static constexpr size_t W2B  = B1B + 3*128;
static constexpr size_t B2B  = W2B + 3*256*128;
static constexpr size_t W1C  = B2B + 3*256;
static constexpr size_t B1C  = W1C + 3*512*260;
static constexpr size_t W2C  = B1C + 3*512;
static constexpr size_t B2C  = W2C + 3*512*512;
static constexpr size_t FW1  = B2C + 3*512;
static constexpr size_t FB1  = FW1 + 3*256*512;
static constexpr size_t FG1  = FB1 + 3*256;
static constexpr size_t FBE1 = FG1 + 3*256;
static constexpr size_t FW2  = FBE1 + 3*256;
static constexpr size_t FB2  = FW2 + 3*128*256;
static constexpr size_t FG2  = FB2 + 3*128;
static constexpr size_t FBE2 = FG2 + 3*128;
static constexpr size_t OFF_KNN1 = FBE2 + 3*128;
static constexpr size_t OFF_KNN2 = OFF_KNN1 + (size_t)BB*S1*16;
static constexpr size_t OFF_W1BF = OFF_KNN2 + (size_t)BB*S2*48;
static constexpr size_t OFF_W2BF = OFF_W1BF + 30720;
static constexpr size_t OFF_W1CBH = OFF_W2BF + 49152;
static constexpr size_t OFF_W1CBL = OFF_W1CBH + 221184;
static constexpr size_t OFF_W2CBH = OFF_W1CBL + 221184;
static constexpr size_t OFF_W2CBL = OFF_W2CBH + 393216;
static constexpr size_t OFF_X3BH  = OFF_W2CBL + 393216;
static constexpr size_t OFF_X3BL  = OFF_X3BH + 1769472;
static constexpr size_t OFF_H3BH  = OFF_X3BL + 1769472;
static constexpr size_t OFF_H3BL  = OFF_H3BH + 3145728;
static constexpr size_t OFF_W2ABH = OFF_H3BL + 3145728;
static constexpr size_t OFF_W2ABL = OFF_W2ABH + 12288;
static constexpr size_t WS_FLOATS = OFF_W2ABL + 12288;

__device__ __align__(16) float g_ws[WS_FLOATS];
__device__ int g_is_f32;
__device__ int g_flip;
__device__ int g_bad;
__device__ int g_nz;

DEVI float bf2f(const __hip_bfloat16 v){ return __bfloat162float(v); }
DEVI float rn_add(float a, float b){ return __fadd_rn(a,b); }
DEVI float rn_mul(float a, float b){ return __fmul_rn(a,b); }
DEVI float rn_sub(float a, float b){ return __fsub_rn(a,b); }
DEVI float sq3(float x,float y,float z){ return rn_add(rn_add(rn_mul(x,x),rn_mul(y,y)),rn_mul(z,z)); }

DEVI float ldany(const void* s, size_t i, int isf){
  return isf ? ((const float*)s)[i] : bf2f(((const __hip_bfloat16*)s)[i]);
}
DEVI unsigned short f2bf(float f){
  unsigned u = __float_as_uint(f);
  unsigned r = (u + 0x7FFFu + ((u>>16)&1u)) >> 16;
  return (unsigned short)r;
}
DEVI float bfbits2f(unsigned short h){ return __uint_as_float(((unsigned)h)<<16); }
DEVI void mfma16(f32x4& d, s16x8 a, s16x8 b){
  asm volatile("v_mfma_f32_16x16x32_bf16 %0, %1, %2, %0" : "+v"(d) : "v"(a), "v"(b));
}
DEVI void mfma_guard(f32x4& d){
  asm volatile("s_nop 7\n\ts_nop 7\n\ts_nop 2" : "+v"(d));
}

// DPP helpers (validated R12). old = self -> boundary lanes no-op.
#define DPPF(dst, src, CTRL) dst = __uint_as_float((unsigned)__builtin_amdgcn_update_dpp(\
    (int)__float_as_uint(src), (int)__float_as_uint(src), CTRL, 0xF, 0xF, false))
#define DPPI(dst, src, CTRL) dst = __builtin_amdgcn_update_dpp(src, src, CTRL, 0xF, 0xF, false)
#define RED_STEP(CTRL) { float ov; int oi; DPPF(ov, best, CTRL); DPPI(oi, bidx, CTRL); \
  if (ov > best || (ov == best && oi < bidx)){ best = ov; bidx = oi; } }
#define WAVE_ARGMAX() RED_STEP(0xB1) RED_STEP(0x4E) RED_STEP(0x124) RED_STEP(0x128) RED_STEP(0x142) RED_STEP(0x143)

// ---------------- init + dtype detection ----------------
__global__ __launch_bounds__(256) void init_detect_kernel(const void* __restrict__ pc){
  __shared__ int s_cnt[256];
  int t = threadIdx.x;
  if (t==0){ g_flip=0; g_bad=0; g_nz=0; }
  const unsigned short* h = (const unsigned short*)pc;
  int weird = 0;
  for (int i=t; i<4096; i+=256){
    unsigned short v = h[2*i];
    int e = (v >> 7) & 0xFF;
    if (e == 0xFF || e < 90 || e > 140) weird++;
  }
  s_cnt[t] = weird; __syncthreads();
  for (int o=128;o>0;o>>=1){ if (t<o) s_cnt[t]+=s_cnt[t+o]; __syncthreads(); }
  if (t==0) g_is_f32 = (s_cnt[0] > 1024) ? 1 : 0;
}

// ---------------- fused param-convert + prep_xyz ----------------
struct ParamPtrs { const void* p[20]; };

DEVI void cvt_arr(const void* s, float* d, int n, int g, int gs, int isf){
  for (int i=g;i<n;i+=gs) d[i] = ldany(s,i,isf);
}
DEVI void cvt_pad(const void* s, float* d, int rows, int cin, int cinp, int g, int gs, int isf){
  int tot = rows*cinp;
  for (int i=g;i<tot;i+=gs){ int r=i/cinp, c=i%cinp; d[i] = (c<cin)? ldany(s,(size_t)r*cin+c,isf) : 0.f; }
}

// blocks 0-255: prep_xyz; blocks 256-767: cvt_params
__global__ __launch_bounds__(256) void cvtprep_kernel(ParamPtrs pp, const void* __restrict__ pc, int mode){
  if (mode==1 && g_flip==0) return;
  const int isf = g_is_f32 ^ mode;
  if (blockIdx.x < 256){
    int i = blockIdx.x*256 + threadIdx.x;
    int b = i >> 11, n = i & 2047;
    float x = ldany(pc, (size_t)(b*3+0)*2048 + n, isf);
    float y = ldany(pc, (size_t)(b*3+1)*2048 + n, isf);
    float z = ldany(pc, (size_t)(b*3+2)*2048 + n, isf);
    g_ws[OFF_XS+i]=x; g_ws[OFF_YS+i]=y; g_ws[OFF_ZS+i]=z;
    g_ws[OFF_SSQ+i]=sq3(x,y,z);
    return;
  }
  int g = (blockIdx.x-256)*256 + threadIdx.x; int gs = 512*256;
  float* ws = g_ws;
  cvt_arr(pp.p[0],  ws+W1A, 3*64*6, g, gs, isf);
  cvt_arr(pp.p[1],  ws+B1A, 3*64, g, gs, isf);
  cvt_arr(pp.p[2],  ws+W2A, 3*128*64, g, gs, isf);
  cvt_arr(pp.p[3],  ws+B2A, 3*128, g, gs, isf);
  cvt_pad(pp.p[4],  ws+W1B, 3*128, 131, 132, g, gs, isf);
  cvt_arr(pp.p[5],  ws+B1B, 3*128, g, gs, isf);
  cvt_arr(pp.p[6],  ws+W2B, 3*256*128, g, gs, isf);
  cvt_arr(pp.p[7],  ws+B2B, 3*256, g, gs, isf);
  cvt_pad(pp.p[8],  ws+W1C, 3*512, 259, 260, g, gs, isf);
  cvt_arr(pp.p[9],  ws+B1C, 3*512, g, gs, isf);
  cvt_arr(pp.p[10], ws+W2C, 3*512*512, g, gs, isf);
  cvt_arr(pp.p[11], ws+B2C, 3*512, g, gs, isf);
  cvt_arr(pp.p[12], ws+FW1, 3*256*512, g, gs, isf);
  cvt_arr(pp.p[13], ws+FB1, 3*256, g, gs, isf);
  cvt_arr(pp.p[14], ws+FG1, 3*256, g, gs, isf);
  cvt_arr(pp.p[15], ws+FBE1,3*256, g, gs, isf);
  cvt_arr(pp.p[16], ws+FW2, 3*128*256, g, gs, isf);
  cvt_arr(pp.p[17], ws+FB2, 3*128, g, gs, isf);
  cvt_arr(pp.p[18], ws+FG2, 3*128, g, gs, isf);
  cvt_arr(pp.p[19], ws+FBE2,3*128, g, gs, isf);
}

// ---------------- fused sanity scans (coords + FW1) ----------------
__global__ __launch_bounds__(256) void scan_check_kernel(){
  size_t off; int n, g, gs;
  if (blockIdx.x < 128){ off = OFF_XS; n = 3*BB*NN; g = blockIdx.x*256 + threadIdx.x; gs = 128*256; }
  else { off = FW1; n = 3*256*512; g = (blockIdx.x-128)*256 + threadIdx.x; gs = 128*256; }
  int bad=0, nz=0;
  for (int i=g;i<n;i+=gs){
    float v = g_ws[off + i];
    if (v != v || fabsf(v) > 1e4f) bad=1;
    if (fabsf(v) > 1e-20f) nz=1;
  }
  unsigned long long mb = __ballot(bad), mn = __ballot(nz);
  if ((threadIdx.x & 63)==0){
    if (mb) atomicOr(&g_bad, 1);
    if (mn) atomicOr(&g_nz, 1);
  }
}

__global__ __launch_bounds__(64) void resolve_flip_kernel(){
  if (threadIdx.x==0){
    g_flip = (g_bad || !g_nz) ? 1 : 0;
    g_bad = 0; g_nz = 0;
  }
}

// ---------------- bf16 weight conversion body ----------------
DEVI void cvt_bf16_body(int g, int gs){
  unsigned short* w1d = (unsigned short*)(g_ws + OFF_W1BF);
  for (int i=g; i<3*128*160; i+=gs){
    int br = i/(128*160); int rem = i%(128*160); int h = rem/160; int c = rem%160;
    float v = (c<132) ? g_ws[W1B + ((size_t)br*128 + h)*132 + c] : 0.f;
    w1d[i] = f2bf(v);
  }
  unsigned short* w2d = (unsigned short*)(g_ws + OFF_W2BF);
  for (int i=g; i<3*256*128; i+=gs) w2d[i] = f2bf(g_ws[W2B + i]);
  unsigned short* w1ch = (unsigned short*)(g_ws + OFF_W1CBH);
  unsigned short* w1cl = (unsigned short*)(g_ws + OFF_W1CBL);
  for (int i=g; i<3*512*288; i+=gs){
    int br = i/(512*288); int rem = i%(512*288); int n = rem/288; int c = rem%288;
    float v = (c<260) ? g_ws[W1C + ((size_t)br*512 + n)*260 + c] : 0.f;
    unsigned short hi = f2bf(v);
    w1ch[i] = hi; w1cl[i] = f2bf(v - bfbits2f(hi));
  }
  unsigned short* w2ch = (unsigned short*)(g_ws + OFF_W2CBH);
  unsigned short* w2cl = (unsigned short*)(g_ws + OFF_W2CBL);
  for (int i=g; i<3*512*512; i+=gs){
    float v = g_ws[W2C + i];
    unsigned short hi = f2bf(v);
    w2ch[i] = hi; w2cl[i] = f2bf(v - bfbits2f(hi));
  }
  unsigned short* w2ah = (unsigned short*)(g_ws + OFF_W2ABH);
  unsigned short* w2al = (unsigned short*)(g_ws + OFF_W2ABL);
  for (int i=g; i<3*128*64; i+=gs){
    float v = g_ws[W2A + i];
    unsigned short hi = f2bf(v);
    w2ah[i] = hi; w2al[i] = f2bf(v - bfbits2f(hi));
  }
}

// ---------------- FPS1: SINGLE WAVE, 32 named-scalar points, DPP argmax, no barriers ----------------
#define FPS_DECL(J) float px##J, py##J, pz##J, dd##J;
#define FPS_LD64(J) { int n=(J)*64+t; px##J=xs[n]; py##J=ys[n]; pz##J=zs[n]; dd##J=1e10f; xl[n]=px##J; yl[n]=py##J; zl[n]=pz##J; }
#define FPS_UPD(J) { float dx=rn_sub(px##J,lx), dy=rn_sub(py##J,ly), dz=rn_sub(pz##J,lz); float d=sq3(dx,dy,dz); dd##J=fminf(dd##J,d); }
#define FPS_T1(J,JA,JB) float v##J; int q##J; { bool c = dd##JB > dd##JA; v##J = c? dd##JB : dd##JA; q##J = c? (JB) : (JA); }
#define FPS_T2(JA,JB) { bool c = v##JB > v##JA; v##JA = c? v##JB : v##JA; q##JA = c? q##JB : q##JA; }

__global__ __launch_bounds__(64,1) void fps1_cvt_kernel(){
  const int t = threadIdx.x;
  if (blockIdx.x >= 32){
    cvt_bf16_body((blockIdx.x-32)*64 + t, 1024*64);
    return;
  }
  const int b = blockIdx.x;
  const float* xs = g_ws + OFF_XS + (size_t)b*NN;
  const float* ys = g_ws + OFF_YS + (size_t)b*NN;
  const float* zs = g_ws + OFF_ZS + (size_t)b*NN;
  float* nx = g_ws + OFF_NX1X + (size_t)b*S1;
  float* ny = g_ws + OFF_NX1Y + (size_t)b*S1;
  float* nz = g_ws + OFF_NX1Z + (size_t)b*S1;
  __shared__ float xl[NN], yl[NN], zl[NN];
  FPS_DECL(0) FPS_DECL(1) FPS_DECL(2) FPS_DECL(3) FPS_DECL(4) FPS_DECL(5) FPS_DECL(6) FPS_DECL(7)
  FPS_DECL(8) FPS_DECL(9) FPS_DECL(10) FPS_DECL(11) FPS_DECL(12) FPS_DECL(13) FPS_DECL(14) FPS_DECL(15)
  FPS_DECL(16) FPS_DECL(17) FPS_DECL(18) FPS_DECL(19) FPS_DECL(20) FPS_DECL(21) FPS_DECL(22) FPS_DECL(23)
  FPS_DECL(24) FPS_DECL(25) FPS_DECL(26) FPS_DECL(27) FPS_DECL(28) FPS_DECL(29) FPS_DECL(30) FPS_DECL(31)
  FPS_LD64(0) FPS_LD64(1) FPS_LD64(2) FPS_LD64(3) FPS_LD64(4) FPS_LD64(5) FPS_LD64(6) FPS_LD64(7)
  FPS_LD64(8) FPS_LD64(9) FPS_LD64(10) FPS_LD64(11) FPS_LD64(12) FPS_LD64(13) FPS_LD64(14) FPS_LD64(15)
  FPS_LD64(16) FPS_LD64(17) FPS_LD64(18) FPS_LD64(19) FPS_LD64(20) FPS_LD64(21) FPS_LD64(22) FPS_LD64(23)
  FPS_LD64(24) FPS_LD64(25) FPS_LD64(26) FPS_LD64(27) FPS_LD64(28) FPS_LD64(29) FPS_LD64(30) FPS_LD64(31)
  // same-wave LDS: in-order, no barrier
  float lx = xl[0], ly = yl[0], lz = zl[0];
  if (t==0){ nx[0]=lx; ny[0]=ly; nz[0]=lz; }
  for (int i=1;i<S1;i++){
    FPS_UPD(0) FPS_UPD(1) FPS_UPD(2) FPS_UPD(3) FPS_UPD(4) FPS_UPD(5) FPS_UPD(6) FPS_UPD(7)
    FPS_UPD(8) FPS_UPD(9) FPS_UPD(10) FPS_UPD(11) FPS_UPD(12) FPS_UPD(13) FPS_UPD(14) FPS_UPD(15)
    FPS_UPD(16) FPS_UPD(17) FPS_UPD(18) FPS_UPD(19) FPS_UPD(20) FPS_UPD(21) FPS_UPD(22) FPS_UPD(23)
    FPS_UPD(24) FPS_UPD(25) FPS_UPD(26) FPS_UPD(27) FPS_UPD(28) FPS_UPD(29) FPS_UPD(30) FPS_UPD(31)
    FPS_T1(0,0,1) FPS_T1(1,2,3) FPS_T1(2,4,5) FPS_T1(3,6,7)
    FPS_T1(4,8,9) FPS_T1(5,10,11) FPS_T1(6,12,13) FPS_T1(7,14,15)
    FPS_T1(8,16,17) FPS_T1(9,18,19) FPS_T1(10,20,21) FPS_T1(11,22,23)
    FPS_T1(12,24,25) FPS_T1(13,26,27) FPS_T1(14,28,29) FPS_T1(15,30,31)
    FPS_T2(0,1) FPS_T2(2,3) FPS_T2(4,5) FPS_T2(6,7)
    FPS_T2(8,9) FPS_T2(10,11) FPS_T2(12,13) FPS_T2(14,15)
    FPS_T2(0,2) FPS_T2(4,6) FPS_T2(8,10) FPS_T2(12,14)
    FPS_T2(0,4) FPS_T2(8,12)
    FPS_T2(0,8)
    float best = v0; int bidx = q0*64 + t;
    WAVE_ARGMAX()
    int gidx = __builtin_amdgcn_readlane(bidx, 63);   // uniform
    lx = xl[gidx]; ly = yl[gidx]; lz = zl[gidx];
    if (t==0){ nx[i]=lx; ny[i]=ly; nz[i]=lz; }
  }
}

// ---------------- KNN1 body ----------------
DEVI void knn1_body(int wid, int lane){
  int b = wid >> 9;
  const float* xs = g_ws + OFF_XS + (size_t)b*NN;
  const float* ys = g_ws + OFF_YS + (size_t)b*NN;
  const float* zs = g_ws + OFF_ZS + (size_t)b*NN;
  const float* sq = g_ws + OFF_SSQ + (size_t)b*NN;
  float cx = g_ws[OFF_NX1X + wid], cy = g_ws[OFF_NX1Y + wid], cz = g_ws[OFF_NX1Z + wid];
  float sc = sq3(cx,cy,cz);
  float d[32];
  #pragma unroll
  for (int c=0;c<32;c++){
    int n = c*64 + lane;
    float x=xs[n], y=ys[n], z=zs[n];
    float dot = rn_add(rn_add(rn_mul(cx,x),rn_mul(cy,y)),rn_mul(cz,z));
    d[c] = rn_sub(rn_add(sc,sq[n]), rn_mul(2.f,dot));
  }
  unsigned sel=0;
  int* out = (int*)(g_ws + OFF_KNN1) + (size_t)wid*16;
  for (int r=0;r<16;r++){
    float tv[16]; int tc[16];
    #pragma unroll
    for (int c=0;c<16;c++){
      float a = ((sel>>(2*c))&1u) ? 3.0e38f : d[2*c];
      float e = ((sel>>(2*c+1))&1u) ? 3.0e38f : d[2*c+1];
      bool cc = e < a;
      tv[c] = cc ? e : a; tc[c] = cc ? (2*c+1) : (2*c);
    }
    #pragma unroll
    for (int s=1; s<16; s<<=1){
      #pragma unroll
      for (int c=0;c<16;c+=2){
        if ((c % (2*s)) == 0 && c+s < 16){
          bool cc = tv[c+s] < tv[c];
          tv[c] = cc ? tv[c+s] : tv[c];
          tc[c] = cc ? tc[c+s] : tc[c];
        }
      }
    }
    float bd = tv[0]; int bi = tc[0]*64 + lane;
    #pragma unroll
    for (int off=32; off>=1; off>>=1){
      float od=__shfl_xor(bd,off); int oi=__shfl_xor(bi,off);
      if (od < bd || (od==bd && oi<bi)){ bd=od; bi=oi; }
    }
    if (lane == (bi & 63)) sel |= 1u << ((unsigned)(bi & 2047) >> 6);
    if (lane == 0) out[r] = bi;
  }
}

// ---------------- FPS2 (blocks 0-31, wave0) + KNN1 (blocks 32-4127) ----------------
__global__ __launch_bounds__(256) void fps2_knn1_kernel(){
  if (blockIdx.x >= 32){
    knn1_body(((blockIdx.x-32)*256 + threadIdx.x) >> 6, threadIdx.x & 63);
    return;
  }
  if (threadIdx.x >= 64) return;
  const int b = blockIdx.x, t = threadIdx.x;
  const float* xs = g_ws + OFF_NX1X + (size_t)b*S1;
  const float* ys = g_ws + OFF_NX1Y + (size_t)b*S1;
  const float* zs = g_ws + OFF_NX1Z + (size_t)b*S1;
  float* nx = g_ws + OFF_NX2X + (size_t)b*S2;
  float* ny = g_ws + OFF_NX2Y + (size_t)b*S2;
  float* nz = g_ws + OFF_NX2Z + (size_t)b*S2;
  __shared__ float xl[S1], yl[S1], zl[S1];
  FPS_DECL(0) FPS_DECL(1) FPS_DECL(2) FPS_DECL(3) FPS_DECL(4) FPS_DECL(5) FPS_DECL(6) FPS_DECL(7)
  FPS_LD64(0) FPS_LD64(1) FPS_LD64(2) FPS_LD64(3) FPS_LD64(4) FPS_LD64(5) FPS_LD64(6) FPS_LD64(7)
  float lx = xl[0], ly = yl[0], lz = zl[0];
  if (t==0){ nx[0]=lx; ny[0]=ly; nz[0]=lz; }
  for (int i=1;i<S2;i++){
    FPS_UPD(0) FPS_UPD(1) FPS_UPD(2) FPS_UPD(3) FPS_UPD(4) FPS_UPD(5) FPS_UPD(6) FPS_UPD(7)
    FPS_T1(0,0,1) FPS_T1(1,2,3) FPS_T1(2,4,5) FPS_T1(3,6,7)
    FPS_T2(0,1) FPS_T2(2,3)
    FPS_T2(0,2)
    float best = v0; int bidx = q0*64 + t;
    WAVE_ARGMAX()
    int gidx = __builtin_amdgcn_readlane(bidx, 63);
    lx = xl[gidx]; ly = yl[gidx]; lz = zl[gidx];
    if (t==0){ nx[i]=lx; ny[i]=ly; nz[i]=lz; }
  }
}

// ---------------- KNN2 body ----------------
DEVI void knn2_body(int wid, int lane){
  int b = wid >> 7;
  const float* xs = g_ws + OFF_NX1X + (size_t)b*S1;
  const float* ys = g_ws + OFF_NX1Y + (size_t)b*S1;
  const float* zs = g_ws + OFF_NX1Z + (size_t)b*S1;
  float cx = g_ws[OFF_NX2X + wid], cy = g_ws[OFF_NX2Y + wid], cz = g_ws[OFF_NX2Z + wid];
  float sc = sq3(cx,cy,cz);
  float d[8];
  #pragma unroll
  for (int c=0;c<8;c++){
    int n = c*64 + lane;
    float x=xs[n], y=ys[n], z=zs[n];
    float sx = sq3(x,y,z);
    float dot = rn_add(rn_add(rn_mul(cx,x),rn_mul(cy,y)),rn_mul(cz,z));
    d[c] = rn_sub(rn_add(sc,sx), rn_mul(2.f,dot));
  }
  unsigned sel=0;
  int* out = (int*)(g_ws + OFF_KNN2) + (size_t)wid*48;
  for (int r=0;r<48;r++){
    float tv[4]; int tc[4];
    #pragma unroll
    for (int c=0;c<4;c++){
      float a = ((sel>>(2*c))&1u) ? 3.0e38f : d[2*c];
      float e = ((sel>>(2*c+1))&1u) ? 3.0e38f : d[2*c+1];
      bool cc = e < a;
      tv[c] = cc ? e : a; tc[c] = cc ? (2*c+1) : (2*c);
    }
    { bool cc = tv[1] < tv[0]; tv[0] = cc?tv[1]:tv[0]; tc[0] = cc?tc[1]:tc[0]; }
    { bool cc = tv[3] < tv[2]; tv[2] = cc?tv[3]:tv[2]; tc[2] = cc?tc[3]:tc[2]; }
    { bool cc = tv[2] < tv[0]; tv[0] = cc?tv[2]:tv[0]; tc[0] = cc?tc[2]:tc[0]; }
    float bd = tv[0]; int bi = tc[0]*64 + lane;
    #pragma unroll
    for (int off=32; off>=1; off>>=1){
      float od=__shfl_xor(bd,off); int oi=__shfl_xor(bi,off);
      if (od < bd || (od==bd && oi<bi)){ bd=od; bi=oi; }
    }
    if (lane == (bi & 63)) sel |= 1u << ((unsigned)(bi & 511) >> 6);
    if (lane == 0) out[r] = bi;
  }
}

// ---------------- KNN2 (blocks 0-1023) + SA1 (blocks 1024-4095) ----------------
__global__ __launch_bounds__(256) void knn2_sa1_kernel(){
  const int t = threadIdx.x;
  if (blockIdx.x < 1024){
    knn2_body((blockIdx.x*256 + t) >> 6, t & 63);
    return;
  }
  const int bx2 = blockIdx.x - 1024;
  const int br = bx2 >> 10;
  const int bxx = bx2 & 1023;
  const int wave = t>>6, lane = t&63, quad = lane>>4, l16 = lane&15;
  __shared__ float w1s[384];
  __shared__ float b1s[64];
  __shared__ __align__(16) short Hh[4][16*72];
  __shared__ __align__(16) short Hl[4][16*72];
  for (int i=t;i<384;i+=256) w1s[i] = g_ws[W1A + (size_t)br*384 + i];
  if (t<64) b1s[t] = g_ws[B1A + br*64 + t];
  __syncthreads();
  const int* kn = (const int*)(g_ws + OFF_KNN1);
  const short* w2h = (const short*)(g_ws + OFF_W2ABH) + (size_t)br*128*64;
  const short* w2l = (const short*)(g_ws + OFF_W2ABL) + (size_t)br*128*64;
  const float* b2 = g_ws + B2A + br*128;
  for (int it=0; it<4; it++){
    int gid = bxx*16 + it*4 + wave;
    int b = gid >> 9;
    int idx = kn[(size_t)gid*16 + l16] & (NN-1);
    float cx = g_ws[OFF_NX1X+gid], cy = g_ws[OFF_NX1Y+gid], cz = g_ws[OFF_NX1Z+gid];
    size_t gl = (size_t)b*NN + idx;
    float x = g_ws[OFF_XS+gl], y = g_ws[OFF_YS+gl], z = g_ws[OFF_ZS+gl];
    float f0=x-cx, f1=y-cy, f2=z-cz;
    #pragma unroll
    for (int i=0;i<16;i++){
      int h = quad*16 + i;
      float acc = b1s[h];
      acc += f0*w1s[h*6+0] + f1*w1s[h*6+1] + f2*w1s[h*6+2]
           +  x*w1s[h*6+3] +  y*w1s[h*6+4] +  z*w1s[h*6+5];
      acc = fmaxf(acc, 0.f);
      unsigned short hi = f2bf(acc);
      Hh[wave][l16*72 + h] = (short)hi;
      Hl[wave][l16*72 + h] = (short)f2bf(acc - bfbits2f(hi));
    }
    __syncthreads();
    s16x8 ah[2], al[2];
    #pragma unroll
    for (int ks=0;ks<2;ks++){
      ah[ks] = *(const s16x8*)(&Hh[wave][l16*72 + ks*32 + quad*8]);
      al[ks] = *(const s16x8*)(&Hl[wave][l16*72 + ks*32 + quad*8]);
    }
    float* P1g = g_ws + OFF_P1 + ((size_t)br*16384 + gid)*128;
    #pragma unroll
    for (int ni=0; ni<8; ni++){
      int o = ni*16 + l16;
      f32x4 acc = {0.f,0.f,0.f,0.f};
      #pragma unroll
      for (int ks=0; ks<2; ks++){
        s16x8 bh = *(const s16x8*)(w2h + (size_t)o*64 + ks*32 + quad*8);
        s16x8 bl = *(const s16x8*)(w2l + (size_t)o*64 + ks*32 + quad*8);
        mfma16(acc, ah[ks], bh);
        mfma16(acc, ah[ks], bl);
        mfma16(acc, al[ks], bh);
      }
      mfma_guard(acc);
      float vmax = fmaxf(fmaxf(acc[0],acc[1]), fmaxf(acc[2],acc[3]));
      vmax = fmaxf(vmax, __shfl_xor(vmax,16));
      vmax = fmaxf(vmax, __shfl_xor(vmax,32));
      if (quad==0) P1g[o] = vmax + b2[o];
    }
  }
}

// ---------------- SA2 (all branches) -> X3 bf16 hi/lo ----------------
template<int K>
DEVI void sa2_body(int br, int g2, short* Xb, short* Hb, float* ctr, int* idxs){
  constexpr int MT = K/16;
  const int b = g2 >> 7;
  const int t = threadIdx.x;
  const int wave = t >> 6, lane = t & 63, quad = lane >> 4, l16 = lane & 15;
  const int* kn2 = (const int*)(g_ws + OFF_KNN2) + (size_t)g2*48;
  if (t < K) idxs[t] = kn2[t] & (S1-1);
  if (t < 3) ctr[t] = g_ws[(t==0?OFF_NX2X:(t==1?OFF_NX2Y:OFF_NX2Z)) + g2];
  __syncthreads();
  const float* p1b = g_ws + OFF_P1 + (size_t)br*16384*128;
  for (int e=t; e<K*168; e+=256){
    int k = e/168, j = e%168;
    int idx = idxs[k];
    float v;
    if (j < 3){
      const float* A = (j==0)? g_ws+OFF_NX1X : (j==1)? g_ws+OFF_NX1Y : g_ws+OFF_NX1Z;
      v = A[(size_t)b*S1 + idx] - ctr[j];
    } else if (j < 131){
      v = p1b[((size_t)b*S1 + idx)*128 + (j-3)];
    } else v = 0.f;
    Xb[e] = (short)f2bf(v);
  }
  __syncthreads();
  {
    const short* w1bf = (const short*)(g_ws + OFF_W1BF) + (size_t)br*128*160;
    const float* b1 = g_ws + B1B + br*128;
    for (int ni = wave; ni < 8; ni += 4){
      int h = ni*16 + l16;
      s16x8 bfr[5];
      #pragma unroll
      for (int ks=0;ks<5;ks++) bfr[ks] = *(const s16x8*)(w1bf + (size_t)h*160 + ks*32 + quad*8);
      float bias = b1[h];
      #pragma unroll
      for (int m=0; m<MT; m++){
        f32x4 acc = {0.f,0.f,0.f,0.f};
        #pragma unroll
        for (int ks=0;ks<5;ks++){
          s16x8 a = *(const s16x8*)(&Xb[(m*16 + l16)*168 + ks*32 + quad*8]);
          mfma16(acc, a, bfr[ks]);
        }
        mfma_guard(acc);
        #pragma unroll
        for (int r=0;r<4;r++){
          int row = m*16 + quad*4 + r;
          float hv = fmaxf(acc[r] + bias, 0.f);
          Hb[row*136 + ni*16 + l16] = (short)f2bf(hv);
        }
      }
    }
  }
  __syncthreads();
  {
    const short* w2bf = (const short*)(g_ws + OFF_W2BF) + (size_t)br*256*128;
    const float* b2 = g_ws + B2B + br*256;
    unsigned short* xh = (unsigned short*)(g_ws + OFF_X3BH);
    unsigned short* xlo = (unsigned short*)(g_ws + OFF_X3BL);
    size_t row = (size_t)(br*4096 + g2)*288;
    for (int ni = wave; ni < 16; ni += 4){
      int o = ni*16 + l16;
      s16x8 bfr[4];
      #pragma unroll
      for (int ks=0;ks<4;ks++) bfr[ks] = *(const s16x8*)(w2bf + (size_t)o*128 + ks*32 + quad*8);
      float vmax = -3.4e38f;
      #pragma unroll
      for (int m=0; m<MT; m++){
        f32x4 acc = {0.f,0.f,0.f,0.f};
        #pragma unroll
        for (int ks=0;ks<4;ks++){
          s16x8 a = *(const s16x8*)(&Hb[(m*16 + l16)*136 + ks*32 + quad*8]);
          mfma16(acc, a, bfr[ks]);
        }
        mfma_guard(acc);
        #pragma unroll
        for (int r=0;r<4;r++) vmax = fmaxf(vmax, acc[r]);
      }
      vmax = fmaxf(vmax, __shfl_xor(vmax, 16));
      vmax = fmaxf(vmax, __shfl_xor(vmax, 32));
      if (quad == 0){
        float hv = vmax + b2[o];
        unsigned short hi = f2bf(hv);
        xh[row + 3 + o] = hi;
        xlo[row + 3 + o] = f2bf(hv - bfbits2f(hi));
      }
    }
    if (t < 3){
      float cv = ctr[t];
      unsigned short hi = f2bf(cv);
      xh[row + t] = hi; xlo[row + t] = f2bf(cv - bfbits2f(hi));
    }
    if (t >= 3 && t < 32){ xh[row + 256 + t] = 0; xlo[row + 256 + t] = 0; }
  }
}

__global__ __launch_bounds__(256) void sa2_all_kernel(){
  __shared__ __align__(16) short Xb[48*168];
  __shared__ __align__(16) short Hb[48*136];
  __shared__ float ctr[3];
  __shared__ int idxs[48];
  int br = blockIdx.x >> 12;
  int g2 = blockIdx.x & 4095;
  if (br == 0)      sa2_body<16>(0, g2, Xb, Hb, ctr, idxs);
  else if (br == 1) sa2_body<32>(1, g2, Xb, Hb, ctr, idxs);
  else              sa2_body<48>(2, g2, Xb, Hb, ctr, idxs);
}

// ---------------- SA3 layer1 via MFMA (hi/lo): 288 -> 512 relu ----------------
__global__ __launch_bounds__(256) void sa3l1_mfma_kernel(){
  const int br = blockIdx.y; const int r0 = blockIdx.x*32;
  const int t = threadIdx.x;
  const int wave = t >> 6, lane = t & 63, quad = lane >> 4, l16 = lane & 15;
  const short* xh = (const short*)(g_ws + OFF_X3BH) + (size_t)(br*4096 + r0)*288;
  const short* xl = (const short*)(g_ws + OFF_X3BL) + (size_t)(br*4096 + r0)*288;
  const short* wh = (const short*)(g_ws + OFF_W1CBH) + (size_t)br*512*288;
  const short* wl = (const short*)(g_ws + OFF_W1CBL) + (size_t)br*512*288;
  const float* bias = g_ws + B1C + br*512;
  unsigned short* hh = (unsigned short*)(g_ws + OFF_H3BH) + (size_t)(br*4096 + r0)*512;
  unsigned short* hl = (unsigned short*)(g_ws + OFF_H3BL) + (size_t)(br*4096 + r0)*512;
  f32x4 acc[2][8];
  #pragma unroll
  for (int m=0;m<2;m++)
    #pragma unroll
    for (int ni=0;ni<8;ni++) acc[m][ni] = (f32x4){0.f,0.f,0.f,0.f};
  for (int ks=0; ks<9; ks++){
    s16x8 ah[2], al[2];
    #pragma unroll
    for (int m=0;m<2;m++){
      ah[m] = *(const s16x8*)(xh + (size_t)(m*16+l16)*288 + ks*32 + quad*8);
      al[m] = *(const s16x8*)(xl + (size_t)(m*16+l16)*288 + ks*32 + quad*8);
    }
    #pragma unroll
    for (int ni=0;ni<8;ni++){
      int n = wave*128 + ni*16 + l16;
      s16x8 bh = *(const s16x8*)(wh + (size_t)n*288 + ks*32 + quad*8);
      s16x8 bl = *(const s16x8*)(wl + (size_t)n*288 + ks*32 + quad*8);
      #pragma unroll
      for (int m=0;m<2;m++){
        mfma16(acc[m][ni], ah[m], bh);
        mfma16(acc[m][ni], ah[m], bl);
        mfma16(acc[m][ni], al[m], bh);
      }
    }
  }
  mfma_guard(acc[0][0]);
  #pragma unroll
  for (int m=0;m<2;m++){
    #pragma unroll
    for (int ni=0;ni<8;ni++){
      int col = wave*128 + ni*16 + l16;
      float bs = bias[col];
      #pragma unroll
      for (int r=0;r<4;r++){
        int row = m*16 + quad*4 + r;
        float hv = fmaxf(acc[m][ni][r] + bs, 0.f);
        unsigned short hi = f2bf(hv);
        hh[(size_t)row*512 + col] = hi;
        hl[(size_t)row*512 + col] = f2bf(hv - bfbits2f(hi));
      }
    }
  }
}

// ---------------- SA3 layer2 via MFMA (hi/lo): 512 -> 512, partial max ----------------
__global__ __launch_bounds__(256) void sa3l2_mfma_kernel(){
  const int br = blockIdx.y; const int b = blockIdx.x>>2; const int part = blockIdx.x&3;
  const int t = threadIdx.x;
  const int wave = t >> 6, lane = t & 63, quad = lane >> 4, l16 = lane & 15;
  const int row0 = b*128 + part*32;
  const short* ahp = (const short*)(g_ws + OFF_H3BH) + (size_t)(br*4096 + row0)*512;
  const short* alp = (const short*)(g_ws + OFF_H3BL) + (size_t)(br*4096 + row0)*512;
  const short* wh = (const short*)(g_ws + OFF_W2CBH) + (size_t)br*512*512;
  const short* wl = (const short*)(g_ws + OFF_W2CBL) + (size_t)br*512*512;
  f32x4 acc[2][8];
  #pragma unroll
  for (int m=0;m<2;m++)
    #pragma unroll
    for (int ni=0;ni<8;ni++) acc[m][ni] = (f32x4){0.f,0.f,0.f,0.f};
  for (int ks=0; ks<16; ks++){
    s16x8 ah[2], al[2];
    #pragma unroll
    for (int m=0;m<2;m++){
      ah[m] = *(const s16x8*)(ahp + (size_t)(m*16+l16)*512 + ks*32 + quad*8);
      al[m] = *(const s16x8*)(alp + (size_t)(m*16+l16)*512 + ks*32 + quad*8);
    }
    #pragma unroll
    for (int ni=0;ni<8;ni++){
      int n = wave*128 + ni*16 + l16;
      s16x8 bh = *(const s16x8*)(wh + (size_t)n*512 + ks*32 + quad*8);
      s16x8 bl = *(const s16x8*)(wl + (size_t)n*512 + ks*32 + quad*8);
      #pragma unroll
      for (int m=0;m<2;m++){
        mfma16(acc[m][ni], ah[m], bh);
        mfma16(acc[m][ni], ah[m], bl);
        mfma16(acc[m][ni], al[m], bh);
      }
    }
  }
  mfma_guard(acc[0][0]);
  #pragma unroll
  for (int ni=0;ni<8;ni++){
    float vmax = -3.4e38f;
    #pragma unroll
    for (int m=0;m<2;m++)
      #pragma unroll
      for (int r=0;r<4;r++) vmax = fmaxf(vmax, acc[m][ni][r]);
    vmax = fmaxf(vmax, __shfl_xor(vmax, 16));
    vmax = fmaxf(vmax, __shfl_xor(vmax, 32));
    if (quad == 0){
      int col = wave*128 + ni*16 + l16;
      g_ws[OFF_O3P + (((size_t)br*BB + b)*4 + part)*512 + col] = vmax;
    }
  }
}

// ---------------- FC head + combine fused (f32 out) ----------------
__global__ __launch_bounds__(256) void fc_kernel(float* __restrict__ out, int out_size){
  int br = blockIdx.x >> 5; int b = blockIdx.x & 31; int t = threadIdx.x;
  __shared__ float xin[512]; __shared__ float x1s[256];
  // combine: code[o] = max_p O3P[...] + b2c[o]; write code output chunk + stage in LDS
  const float* o3p = g_ws + OFF_O3P + (((size_t)br*BB + b)*4)*512;
  const float* b2c = g_ws + B2C + br*512;
  #pragma unroll
  for (int k=0;k<2;k++){
    int o = t + k*256;
    float m = fmaxf(fmaxf(o3p[o], o3p[512+o]), fmaxf(o3p[1024+o], o3p[1536+o]));
    m += b2c[o];
    xin[o] = m;
    int oi = 3*BB*128 + ((br*BB + b)*512) + o;
    if (oi < out_size) out[oi] = m;
  }
  __syncthreads();
  const float s = (float)(1.0 / sqrt(1.0 + 1e-5));
  {
    const float4* wp = (const float4*)(g_ws + FW1 + ((size_t)br*256 + t)*512);
    const float4* xp = (const float4*)xin;
    float acc = 0.f;
    #pragma unroll 8
    for (int q=0;q<128;q++){ float4 w4=wp[q], x4=xp[q]; acc += w4.x*x4.x + w4.y*x4.y + w4.z*x4.z + w4.w*x4.w; }
    acc = (acc + g_ws[FB1 + br*256+t]) * s;
    acc = g_ws[FG1+br*256+t]*acc + g_ws[FBE1+br*256+t];
    x1s[t] = fmaxf(acc, 0.f);
  }
  __syncthreads();
  if (t < 128){
    const float4* wp = (const float4*)(g_ws + FW2 + ((size_t)br*128 + t)*256);
    const float4* xp = (const float4*)x1s;
    float acc=0.f;
    #pragma unroll 8
    for (int q=0;q<64;q++){ float4 w4=wp[q], x4=xp[q]; acc += w4.x*x4.x + w4.y*x4.y + w4.z*x4.z + w4.w*x4.w; }
    acc = (acc + g_ws[FB2+br*128+t])*s;
    acc = g_ws[FG2+br*128+t]*acc + g_ws[FBE2+br*128+t];
    int oi = ((size_t)br*BB + b)*128 + t;
    if (oi < out_size) out[oi] = fmaxf(acc,0.f);
  }
}

// ---------------- launch (R13: single-wave fps1 + kernel merges) ----------------
extern "C" void kernel_launch(void* const* d_in, const int* in_sizes, int n_in,
                              void* d_out, int out_size, void* d_ws, size_t ws_size,
                              hipStream_t stream) {
  (void)d_ws; (void)ws_size;
  if (n_in < 21) return;
  if (in_sizes[0] != BB*3*NN) return;
  float* out = (float*)d_out;

  ParamPtrs pp;
  for (int i=0;i<20;i++) pp.p[i] = d_in[i+1];

  init_detect_kernel<<<1,256,0,stream>>>(d_in[0]);
  cvtprep_kernel<<<768,256,0,stream>>>(pp, d_in[0], 0);
  scan_check_kernel<<<256,256,0,stream>>>();
  resolve_flip_kernel<<<1,64,0,stream>>>();
  cvtprep_kernel<<<768,256,0,stream>>>(pp, d_in[0], 1);   // gated on g_flip

  fps1_cvt_kernel<<<32+1024,64,0,stream>>>();             // fps1 (32 blk) + cvt_bf16 (1024 blk)
  fps2_knn1_kernel<<<32+4096,256,0,stream>>>();
  knn2_sa1_kernel<<<1024+3072,256,0,stream>>>();
  sa2_all_kernel<<<3*4096,256,0,stream>>>();

  sa3l1_mfma_kernel<<<dim3(128,3),256,0,stream>>>();
  sa3l2_mfma_kernel<<<dim3(128,3),256,0,stream>>>();
  fc_kernel<<<96,256,0,stream>>>(out, out_size);          // combine fused in
}

// Round 14
// 1371.072 us; speedup vs baseline: 1.0720x; 1.0720x over previous
//
#include <hip/hip_runtime.h>
#include <hip/hip_bf16.h>
#include <math.h>

#define DEVI __device__ __forceinline__

static constexpr int BB = 32, NN = 2048, S1 = 512, S2 = 128;

typedef float f32x4 __attribute__((ext_vector_type(4)));
typedef short s16x8 __attribute__((ext_vector_type(8)));

// ---------------- static workspace layout (float units) ----------------
static constexpr size_t OFF_XS   = 0;
static constexpr size_t OFF_YS   = OFF_XS + (size_t)BB*NN;
static constexpr size_t OFF_ZS   = OFF_YS + (size_t)BB*NN;
static constexpr size_t OFF_SSQ  = OFF_ZS + (size_t)BB*NN;
static constexpr size_t OFF_NX1X = OFF_SSQ + (size_t)BB*NN;
static constexpr size_t OFF_NX1Y = OFF_NX1X + (size_t)BB*S1;
static constexpr size_t OFF_NX1Z = OFF_NX1Y + (size_t)BB*S1;
static constexpr size_t OFF_NX2X = OFF_NX1Z + (size_t)BB*S1;
static constexpr size_t OFF_NX2Y = OFF_NX2X + (size_t)BB*S2;
static constexpr size_t OFF_NX2Z = OFF_NX2Y + (size_t)BB*S2;
static constexpr size_t OFF_CODE = OFF_NX2Z + (size_t)BB*S2;          // (unused)
static constexpr size_t OFF_O3P  = OFF_CODE + (size_t)3*BB*512;
static constexpr size_t OFF_P1   = OFF_O3P + (size_t)3*BB*4*512;
static constexpr size_t OFF_X3   = OFF_P1 + (size_t)3*BB*S1*128;      // (unused)
static constexpr size_t OFF_H3   = OFF_X3 + (size_t)3*BB*S2*260;     // (unused)
static constexpr size_t OFF_W    = OFF_H3 + (size_t)3*BB*S2*512;
static constexpr size_t W1A  = OFF_W;
static constexpr size_t B1A  = W1A + 3*64*6;
static constexpr size_t W2A  = B1A + 3*64;
static constexpr size_t B2A  = W2A + 3*128*64;
static constexpr size_t W1B  = B2A + 3*128;
static constexpr size_t B1B  = W1B + 3*128*132;
static constexpr size_t W2B  = B1B + 3*128;
static constexpr size_t B2B  = W2B + 3*256*128;
static constexpr size_t W1C  = B2B + 3*256;
static constexpr size_t B1C  = W1C + 3*512*260;
static constexpr size_t W2C  = B1C + 3*512;
static constexpr size_t B2C  = W2C + 3*512*512;
static constexpr size_t FW1  = B2C + 3*512;
static constexpr size_t FB1  = FW1 + 3*256*512;
static constexpr size_t FG1  = FB1 + 3*256;
static constexpr size_t FBE1 = FG1 + 3*256;
static constexpr size_t FW2  = FBE1 + 3*256;
static constexpr size_t FB2  = FW2 + 3*128*256;
static constexpr size_t FG2  = FB2 + 3*128;
static constexpr size_t FBE2 = FG2 + 3*128;
static constexpr size_t OFF_KNN1 = FBE2 + 3*128;
static constexpr size_t OFF_KNN2 = OFF_KNN1 + (size_t)BB*S1*16;
static constexpr size_t OFF_W1BF = OFF_KNN2 + (size_t)BB*S2*48;
static constexpr size_t OFF_W2BF = OFF_W1BF + 30720;
static constexpr size_t OFF_W1CBH = OFF_W2BF + 49152;
static constexpr size_t OFF_W1CBL = OFF_W1CBH + 221184;
static constexpr size_t OFF_W2CBH = OFF_W1CBL + 221184;
static constexpr size_t OFF_W2CBL = OFF_W2CBH + 393216;
static constexpr size_t OFF_X3BH  = OFF_W2CBL + 393216;
static constexpr size_t OFF_X3BL  = OFF_X3BH + 1769472;
static constexpr size_t OFF_H3BH  = OFF_X3BL + 1769472;
static constexpr size_t OFF_H3BL  = OFF_H3BH + 3145728;
static constexpr size_t OFF_W2ABH = OFF_H3BL + 3145728;
static constexpr size_t OFF_W2ABL = OFF_W2ABH + 12288;
static constexpr size_t WS_FLOATS = OFF_W2ABL + 12288;

__device__ __align__(16) float g_ws[WS_FLOATS];
__device__ int g_is_f32;
__device__ int g_flip;
__device__ int g_bad;
__device__ int g_nz;

DEVI float bf2f(const __hip_bfloat16 v){ return __bfloat162float(v); }
DEVI float rn_add(float a, float b){ return __fadd_rn(a,b); }
DEVI float rn_mul(float a, float b){ return __fmul_rn(a,b); }
DEVI float rn_sub(float a, float b){ return __fsub_rn(a,b); }
DEVI float sq3(float x,float y,float z){ return rn_add(rn_add(rn_mul(x,x),rn_mul(y,y)),rn_mul(z,z)); }

DEVI float ldany(const void* s, size_t i, int isf){
  return isf ? ((const float*)s)[i] : bf2f(((const __hip_bfloat16*)s)[i]);
}
DEVI unsigned short f2bf(float f){
  unsigned u = __float_as_uint(f);
  unsigned r = (u + 0x7FFFu + ((u>>16)&1u)) >> 16;
  return (unsigned short)r;
}
DEVI float bfbits2f(unsigned short h){ return __uint_as_float(((unsigned)h)<<16); }
DEVI void mfma16(f32x4& d, s16x8 a, s16x8 b){
  asm volatile("v_mfma_f32_16x16x32_bf16 %0, %1, %2, %0" : "+v"(d) : "v"(a), "v"(b));
}
DEVI void mfma_guard(f32x4& d){
  asm volatile("s_nop 7\n\ts_nop 7\n\ts_nop 2" : "+v"(d));
}

// DPP helpers (validated R12). old = self -> boundary lanes no-op.
#define DPPF(dst, src, CTRL) dst = __uint_as_float((unsigned)__builtin_amdgcn_update_dpp(\
    (int)__float_as_uint(src), (int)__float_as_uint(src), CTRL, 0xF, 0xF, false))
#define DPPI(dst, src, CTRL) dst = __builtin_amdgcn_update_dpp(src, src, CTRL, 0xF, 0xF, false)
#define RED_STEP(CTRL) { float ov; int oi; DPPF(ov, best, CTRL); DPPI(oi, bidx, CTRL); \
  if (ov > best || (ov == best && oi < bidx)){ best = ov; bidx = oi; } }
#define WAVE_ARGMAX() RED_STEP(0xB1) RED_STEP(0x4E) RED_STEP(0x124) RED_STEP(0x128) RED_STEP(0x142) RED_STEP(0x143)

// ---------------- init + dtype detection ----------------
__global__ __launch_bounds__(256) void init_detect_kernel(const void* __restrict__ pc){
  __shared__ int s_cnt[256];
  int t = threadIdx.x;
  if (t==0){ g_flip=0; g_bad=0; g_nz=0; }
  const unsigned short* h = (const unsigned short*)pc;
  int weird = 0;
  for (int i=t; i<4096; i+=256){
    unsigned short v = h[2*i];
    int e = (v >> 7) & 0xFF;
    if (e == 0xFF || e < 90 || e > 140) weird++;
  }
  s_cnt[t] = weird; __syncthreads();
  for (int o=128;o>0;o>>=1){ if (t<o) s_cnt[t]+=s_cnt[t+o]; __syncthreads(); }
  if (t==0) g_is_f32 = (s_cnt[0] > 1024) ? 1 : 0;
}

// ---------------- fused param-convert + prep_xyz ----------------
struct ParamPtrs { const void* p[20]; };

DEVI void cvt_arr(const void* s, float* d, int n, int g, int gs, int isf){
  for (int i=g;i<n;i+=gs) d[i] = ldany(s,i,isf);
}
DEVI void cvt_pad(const void* s, float* d, int rows, int cin, int cinp, int g, int gs, int isf){
  int tot = rows*cinp;
  for (int i=g;i<tot;i+=gs){ int r=i/cinp, c=i%cinp; d[i] = (c<cin)? ldany(s,(size_t)r*cin+c,isf) : 0.f; }
}

// blocks 0-255: prep_xyz; blocks 256-767: cvt_params
__global__ __launch_bounds__(256) void cvtprep_kernel(ParamPtrs pp, const void* __restrict__ pc, int mode){
  if (mode==1 && g_flip==0) return;
  const int isf = g_is_f32 ^ mode;
  if (blockIdx.x < 256){
    int i = blockIdx.x*256 + threadIdx.x;
    int b = i >> 11, n = i & 2047;
    float x = ldany(pc, (size_t)(b*3+0)*2048 + n, isf);
    float y = ldany(pc, (size_t)(b*3+1)*2048 + n, isf);
    float z = ldany(pc, (size_t)(b*3+2)*2048 + n, isf);
    g_ws[OFF_XS+i]=x; g_ws[OFF_YS+i]=y; g_ws[OFF_ZS+i]=z;
    g_ws[OFF_SSQ+i]=sq3(x,y,z);
    return;
  }
  int g = (blockIdx.x-256)*256 + threadIdx.x; int gs = 512*256;
  float* ws = g_ws;
  cvt_arr(pp.p[0],  ws+W1A, 3*64*6, g, gs, isf);
  cvt_arr(pp.p[1],  ws+B1A, 3*64, g, gs, isf);
  cvt_arr(pp.p[2],  ws+W2A, 3*128*64, g, gs, isf);
  cvt_arr(pp.p[3],  ws+B2A, 3*128, g, gs, isf);
  cvt_pad(pp.p[4],  ws+W1B, 3*128, 131, 132, g, gs, isf);
  cvt_arr(pp.p[5],  ws+B1B, 3*128, g, gs, isf);
  cvt_arr(pp.p[6],  ws+W2B, 3*256*128, g, gs, isf);
  cvt_arr(pp.p[7],  ws+B2B, 3*256, g, gs, isf);
  cvt_pad(pp.p[8],  ws+W1C, 3*512, 259, 260, g, gs, isf);
  cvt_arr(pp.p[9],  ws+B1C, 3*512, g, gs, isf);
  cvt_arr(pp.p[10], ws+W2C, 3*512*512, g, gs, isf);
  cvt_arr(pp.p[11], ws+B2C, 3*512, g, gs, isf);
  cvt_arr(pp.p[12], ws+FW1, 3*256*512, g, gs, isf);
  cvt_arr(pp.p[13], ws+FB1, 3*256, g, gs, isf);
  cvt_arr(pp.p[14], ws+FG1, 3*256, g, gs, isf);
  cvt_arr(pp.p[15], ws+FBE1,3*256, g, gs, isf);
  cvt_arr(pp.p[16], ws+FW2, 3*128*256, g, gs, isf);
  cvt_arr(pp.p[17], ws+FB2, 3*128, g, gs, isf);
  cvt_arr(pp.p[18], ws+FG2, 3*128, g, gs, isf);
  cvt_arr(pp.p[19], ws+FBE2,3*128, g, gs, isf);
}

// ---------------- fused sanity scans (coords + FW1) ----------------
__global__ __launch_bounds__(256) void scan_check_kernel(){
  size_t off; int n, g, gs;
  if (blockIdx.x < 128){ off = OFF_XS; n = 3*BB*NN; g = blockIdx.x*256 + threadIdx.x; gs = 128*256; }
  else { off = FW1; n = 3*256*512; g = (blockIdx.x-128)*256 + threadIdx.x; gs = 128*256; }
  int bad=0, nz=0;
  for (int i=g;i<n;i+=gs){
    float v = g_ws[off + i];
    if (v != v || fabsf(v) > 1e4f) bad=1;
    if (fabsf(v) > 1e-20f) nz=1;
  }
  unsigned long long mb = __ballot(bad), mn = __ballot(nz);
  if ((threadIdx.x & 63)==0){
    if (mb) atomicOr(&g_bad, 1);
    if (mn) atomicOr(&g_nz, 1);
  }
}

__global__ __launch_bounds__(64) void resolve_flip_kernel(){
  if (threadIdx.x==0){
    g_flip = (g_bad || !g_nz) ? 1 : 0;
    g_bad = 0; g_nz = 0;
  }
}

// ---------------- bf16 weight conversion body ----------------
DEVI void cvt_bf16_body(int g, int gs){
  unsigned short* w1d = (unsigned short*)(g_ws + OFF_W1BF);
  for (int i=g; i<3*128*160; i+=gs){
    int br = i/(128*160); int rem = i%(128*160); int h = rem/160; int c = rem%160;
    float v = (c<132) ? g_ws[W1B + ((size_t)br*128 + h)*132 + c] : 0.f;
    w1d[i] = f2bf(v);
  }
  unsigned short* w2d = (unsigned short*)(g_ws + OFF_W2BF);
  for (int i=g; i<3*256*128; i+=gs) w2d[i] = f2bf(g_ws[W2B + i]);
  unsigned short* w1ch = (unsigned short*)(g_ws + OFF_W1CBH);
  unsigned short* w1cl = (unsigned short*)(g_ws + OFF_W1CBL);
  for (int i=g; i<3*512*288; i+=gs){
    int br = i/(512*288); int rem = i%(512*288); int n = rem/288; int c = rem%288;
    float v = (c<260) ? g_ws[W1C + ((size_t)br*512 + n)*260 + c] : 0.f;
    unsigned short hi = f2bf(v);
    w1ch[i] = hi; w1cl[i] = f2bf(v - bfbits2f(hi));
  }
  unsigned short* w2ch = (unsigned short*)(g_ws + OFF_W2CBH);
  unsigned short* w2cl = (unsigned short*)(g_ws + OFF_W2CBL);
  for (int i=g; i<3*512*512; i+=gs){
    float v = g_ws[W2C + i];
    unsigned short hi = f2bf(v);
    w2ch[i] = hi; w2cl[i] = f2bf(v - bfbits2f(hi));
  }
  unsigned short* w2ah = (unsigned short*)(g_ws + OFF_W2ABH);
  unsigned short* w2al = (unsigned short*)(g_ws + OFF_W2ABL);
  for (int i=g; i<3*128*64; i+=gs){
    float v = g_ws[W2A + i];
    unsigned short hi = f2bf(v);
    w2ah[i] = hi; w2al[i] = f2bf(v - bfbits2f(hi));
  }
}

// ---------------- FPS1 (R12-proven): 128 thr x 16 named scalars, DPP + parity LDS combine ----------------
#define FPS_DECL(J) float px##J, py##J, pz##J, dd##J;
#define FPS_LOAD1(J) { int n=(J)*128+t; px##J=xs[n]; py##J=ys[n]; pz##J=zs[n]; dd##J=1e10f; xl[n]=px##J; yl[n]=py##J; zl[n]=pz##J; }
#define FPS_LD64(J) { int n=(J)*64+t; px##J=xs[n]; py##J=ys[n]; pz##J=zs[n]; dd##J=1e10f; xl[n]=px##J; yl[n]=py##J; zl[n]=pz##J; }
#define FPS_UPD(J) { float dx=rn_sub(px##J,lx), dy=rn_sub(py##J,ly), dz=rn_sub(pz##J,lz); float d=sq3(dx,dy,dz); dd##J=fminf(dd##J,d); }
#define FPS_T1(J,JA,JB) float v##J; int q##J; { bool c = dd##JB > dd##JA; v##J = c? dd##JB : dd##JA; q##J = c? (JB) : (JA); }
#define FPS_T2(JA,JB) { bool c = v##JB > v##JA; v##JA = c? v##JB : v##JA; q##JA = c? q##JB : q##JA; }

__global__ __launch_bounds__(128,1) void fps1_cvt_kernel(){
  const int t = threadIdx.x;
  if (blockIdx.x >= 32){
    cvt_bf16_body((blockIdx.x-32)*128 + t, 512*128);
    return;
  }
  const int b = blockIdx.x;
  const int wave = t >> 6;
  const float* xs = g_ws + OFF_XS + (size_t)b*NN;
  const float* ys = g_ws + OFF_YS + (size_t)b*NN;
  const float* zs = g_ws + OFF_ZS + (size_t)b*NN;
  float* nx = g_ws + OFF_NX1X + (size_t)b*S1;
  float* ny = g_ws + OFF_NX1Y + (size_t)b*S1;
  float* nz = g_ws + OFF_NX1Z + (size_t)b*S1;
  __shared__ float xl[NN], yl[NN], zl[NN];
  __shared__ float s_val[2][2]; __shared__ int s_idx[2][2];
  FPS_DECL(0) FPS_DECL(1) FPS_DECL(2) FPS_DECL(3) FPS_DECL(4) FPS_DECL(5) FPS_DECL(6) FPS_DECL(7)
  FPS_DECL(8) FPS_DECL(9) FPS_DECL(10) FPS_DECL(11) FPS_DECL(12) FPS_DECL(13) FPS_DECL(14) FPS_DECL(15)
  FPS_LOAD1(0) FPS_LOAD1(1) FPS_LOAD1(2) FPS_LOAD1(3) FPS_LOAD1(4) FPS_LOAD1(5) FPS_LOAD1(6) FPS_LOAD1(7)
  FPS_LOAD1(8) FPS_LOAD1(9) FPS_LOAD1(10) FPS_LOAD1(11) FPS_LOAD1(12) FPS_LOAD1(13) FPS_LOAD1(14) FPS_LOAD1(15)
  __syncthreads();
  float lx = xl[0], ly = yl[0], lz = zl[0];
  if (t==0){ nx[0]=lx; ny[0]=ly; nz[0]=lz; }
  for (int i=1;i<S1;i++){
    FPS_UPD(0) FPS_UPD(1) FPS_UPD(2) FPS_UPD(3) FPS_UPD(4) FPS_UPD(5) FPS_UPD(6) FPS_UPD(7)
    FPS_UPD(8) FPS_UPD(9) FPS_UPD(10) FPS_UPD(11) FPS_UPD(12) FPS_UPD(13) FPS_UPD(14) FPS_UPD(15)
    FPS_T1(0,0,1) FPS_T1(1,2,3) FPS_T1(2,4,5) FPS_T1(3,6,7)
    FPS_T1(4,8,9) FPS_T1(5,10,11) FPS_T1(6,12,13) FPS_T1(7,14,15)
    FPS_T2(0,1) FPS_T2(2,3) FPS_T2(4,5) FPS_T2(6,7)
    FPS_T2(0,2) FPS_T2(4,6)
    FPS_T2(0,4)
    float best = v0; int bidx = q0*128 + t;
    WAVE_ARGMAX()                                   // lane 63 of each wave holds wave argmax
    int par = i & 1;
    if ((t&63)==63){ s_val[par][wave]=best; s_idx[par][wave]=bidx; }
    __syncthreads();
    float va = s_val[par][0], vb = s_val[par][1];
    int ia = s_idx[par][0], ib = s_idx[par][1];
    int gidx = (vb > va || (vb == va && ib < ia)) ? ib : ia;
    lx = xl[gidx]; ly = yl[gidx]; lz = zl[gidx];
    if (t==0){ nx[i]=lx; ny[i]=ly; nz[i]=lz; }
  }
}

// ---------------- KNN1 body ----------------
DEVI void knn1_body(int wid, int lane){
  int b = wid >> 9;
  const float* xs = g_ws + OFF_XS + (size_t)b*NN;
  const float* ys = g_ws + OFF_YS + (size_t)b*NN;
  const float* zs = g_ws + OFF_ZS + (size_t)b*NN;
  const float* sq = g_ws + OFF_SSQ + (size_t)b*NN;
  float cx = g_ws[OFF_NX1X + wid], cy = g_ws[OFF_NX1Y + wid], cz = g_ws[OFF_NX1Z + wid];
  float sc = sq3(cx,cy,cz);
  float d[32];
  #pragma unroll
  for (int c=0;c<32;c++){
    int n = c*64 + lane;
    float x=xs[n], y=ys[n], z=zs[n];
    float dot = rn_add(rn_add(rn_mul(cx,x),rn_mul(cy,y)),rn_mul(cz,z));
    d[c] = rn_sub(rn_add(sc,sq[n]), rn_mul(2.f,dot));
  }
  unsigned sel=0;
  int* out = (int*)(g_ws + OFF_KNN1) + (size_t)wid*16;
  for (int r=0;r<16;r++){
    float tv[16]; int tc[16];
    #pragma unroll
    for (int c=0;c<16;c++){
      float a = ((sel>>(2*c))&1u) ? 3.0e38f : d[2*c];
      float e = ((sel>>(2*c+1))&1u) ? 3.0e38f : d[2*c+1];
      bool cc = e < a;
      tv[c] = cc ? e : a; tc[c] = cc ? (2*c+1) : (2*c);
    }
    #pragma unroll
    for (int s=1; s<16; s<<=1){
      #pragma unroll
      for (int c=0;c<16;c+=2){
        if ((c % (2*s)) == 0 && c+s < 16){
          bool cc = tv[c+s] < tv[c];
          tv[c] = cc ? tv[c+s] : tv[c];
          tc[c] = cc ? tc[c+s] : tc[c];
        }
      }
    }
    float bd = tv[0]; int bi = tc[0]*64 + lane;
    #pragma unroll
    for (int off=32; off>=1; off>>=1){
      float od=__shfl_xor(bd,off); int oi=__shfl_xor(bi,off);
      if (od < bd || (od==bd && oi<bi)){ bd=od; bi=oi; }
    }
    if (lane == (bi & 63)) sel |= 1u << ((unsigned)(bi & 2047) >> 6);
    if (lane == 0) out[r] = bi;
  }
}

// ---------------- FPS2 (blocks 0-31, wave0) + KNN1 (blocks 32-4127) ----------------
__global__ __launch_bounds__(256) void fps2_knn1_kernel(){
  if (blockIdx.x >= 32){
    knn1_body(((blockIdx.x-32)*256 + threadIdx.x) >> 6, threadIdx.x & 63);
    return;
  }
  if (threadIdx.x >= 64) return;
  const int b = blockIdx.x, t = threadIdx.x;
  const float* xs = g_ws + OFF_NX1X + (size_t)b*S1;
  const float* ys = g_ws + OFF_NX1Y + (size_t)b*S1;
  const float* zs = g_ws + OFF_NX1Z + (size_t)b*S1;
  float* nx = g_ws + OFF_NX2X + (size_t)b*S2;
  float* ny = g_ws + OFF_NX2Y + (size_t)b*S2;
  float* nz = g_ws + OFF_NX2Z + (size_t)b*S2;
  __shared__ float xl[S1], yl[S1], zl[S1];
  FPS_DECL(0) FPS_DECL(1) FPS_DECL(2) FPS_DECL(3) FPS_DECL(4) FPS_DECL(5) FPS_DECL(6) FPS_DECL(7)
  FPS_LD64(0) FPS_LD64(1) FPS_LD64(2) FPS_LD64(3) FPS_LD64(4) FPS_LD64(5) FPS_LD64(6) FPS_LD64(7)
  float lx = xl[0], ly = yl[0], lz = zl[0];
  if (t==0){ nx[0]=lx; ny[0]=ly; nz[0]=lz; }
  for (int i=1;i<S2;i++){
    FPS_UPD(0) FPS_UPD(1) FPS_UPD(2) FPS_UPD(3) FPS_UPD(4) FPS_UPD(5) FPS_UPD(6) FPS_UPD(7)
    FPS_T1(0,0,1) FPS_T1(1,2,3) FPS_T1(2,4,5) FPS_T1(3,6,7)
    FPS_T2(0,1) FPS_T2(2,3)
    FPS_T2(0,2)
    float best = v0; int bidx = q0*64 + t;
    WAVE_ARGMAX()
    int gidx = __builtin_amdgcn_readlane(bidx, 63);
    lx = xl[gidx]; ly = yl[gidx]; lz = zl[gidx];
    if (t==0){ nx[i]=lx; ny[i]=ly; nz[i]=lz; }
  }
}

// ---------------- KNN2 body ----------------
DEVI void knn2_body(int wid, int lane){
  int b = wid >> 7;
  const float* xs = g_ws + OFF_NX1X + (size_t)b*S1;
  const float* ys = g_ws + OFF_NX1Y + (size_t)b*S1;
  const float* zs = g_ws + OFF_NX1Z + (size_t)b*S1;
  float cx = g_ws[OFF_NX2X + wid], cy = g_ws[OFF_NX2Y + wid], cz = g_ws[OFF_NX2Z + wid];
  float sc = sq3(cx,cy,cz);
  float d[8];
  #pragma unroll
  for (int c=0;c<8;c++){
    int n = c*64 + lane;
    float x=xs[n], y=ys[n], z=zs[n];
    float sx = sq3(x,y,z);
    float dot = rn_add(rn_add(rn_mul(cx,x),rn_mul(cy,y)),rn_mul(cz,z));
    d[c] = rn_sub(rn_add(sc,sx), rn_mul(2.f,dot));
  }
  unsigned sel=0;
  int* out = (int*)(g_ws + OFF_KNN2) + (size_t)wid*48;
  for (int r=0;r<48;r++){
    float tv[4]; int tc[4];
    #pragma unroll
    for (int c=0;c<4;c++){
      float a = ((sel>>(2*c))&1u) ? 3.0e38f : d[2*c];
      float e = ((sel>>(2*c+1))&1u) ? 3.0e38f : d[2*c+1];
      bool cc = e < a;
      tv[c] = cc ? e : a; tc[c] = cc ? (2*c+1) : (2*c);
    }
    { bool cc = tv[1] < tv[0]; tv[0] = cc?tv[1]:tv[0]; tc[0] = cc?tc[1]:tc[0]; }
    { bool cc = tv[3] < tv[2]; tv[2] = cc?tv[3]:tv[2]; tc[2] = cc?tc[3]:tc[2]; }
    { bool cc = tv[2] < tv[0]; tv[0] = cc?tv[2]:tv[0]; tc[0] = cc?tc[2]:tc[0]; }
    float bd = tv[0]; int bi = tc[0]*64 + lane;
    #pragma unroll
    for (int off=32; off>=1; off>>=1){
      float od=__shfl_xor(bd,off); int oi=__shfl_xor(bi,off);
      if (od < bd || (od==bd && oi<bi)){ bd=od; bi=oi; }
    }
    if (lane == (bi & 63)) sel |= 1u << ((unsigned)(bi & 511) >> 6);
    if (lane == 0) out[r] = bi;
  }
}

// ---------------- KNN2 (blocks 0-1023) + SA1 (blocks 1024-4095) ----------------
__global__ __launch_bounds__(256) void knn2_sa1_kernel(){
  const int t = threadIdx.x;
  if (blockIdx.x < 1024){
    knn2_body((blockIdx.x*256 + t) >> 6, t & 63);
    return;
  }
  const int bx2 = blockIdx.x - 1024;
  const int br = bx2 >> 10;
  const int bxx = bx2 & 1023;
  const int wave = t>>6, lane = t&63, quad = lane>>4, l16 = lane&15;
  __shared__ float w1s[384];
  __shared__ float b1s[64];
  __shared__ __align__(16) short Hh[4][16*72];
  __shared__ __align__(16) short Hl[4][16*72];
  for (int i=t;i<384;i+=256) w1s[i] = g_ws[W1A + (size_t)br*384 + i];
  if (t<64) b1s[t] = g_ws[B1A + br*64 + t];
  __syncthreads();
  const int* kn = (const int*)(g_ws + OFF_KNN1);
  const short* w2h = (const short*)(g_ws + OFF_W2ABH) + (size_t)br*128*64;
  const short* w2l = (const short*)(g_ws + OFF_W2ABL) + (size_t)br*128*64;
  const float* b2 = g_ws + B2A + br*128;
  for (int it=0; it<4; it++){
    int gid = bxx*16 + it*4 + wave;
    int b = gid >> 9;
    int idx = kn[(size_t)gid*16 + l16] & (NN-1);
    float cx = g_ws[OFF_NX1X+gid], cy = g_ws[OFF_NX1Y+gid], cz = g_ws[OFF_NX1Z+gid];
    size_t gl = (size_t)b*NN + idx;
    float x = g_ws[OFF_XS+gl], y = g_ws[OFF_YS+gl], z = g_ws[OFF_ZS+gl];
    float f0=x-cx, f1=y-cy, f2=z-cz;
    #pragma unroll
    for (int i=0;i<16;i++){
      int h = quad*16 + i;
      float acc = b1s[h];
      acc += f0*w1s[h*6+0] + f1*w1s[h*6+1] + f2*w1s[h*6+2]
           +  x*w1s[h*6+3] +  y*w1s[h*6+4] +  z*w1s[h*6+5];
      acc = fmaxf(acc, 0.f);
      unsigned short hi = f2bf(acc);
      Hh[wave][l16*72 + h] = (short)hi;
      Hl[wave][l16*72 + h] = (short)f2bf(acc - bfbits2f(hi));
    }
    __syncthreads();
    s16x8 ah[2], al[2];
    #pragma unroll
    for (int ks=0;ks<2;ks++){
      ah[ks] = *(const s16x8*)(&Hh[wave][l16*72 + ks*32 + quad*8]);
      al[ks] = *(const s16x8*)(&Hl[wave][l16*72 + ks*32 + quad*8]);
    }
    float* P1g = g_ws + OFF_P1 + ((size_t)br*16384 + gid)*128;
    #pragma unroll
    for (int ni=0; ni<8; ni++){
      int o = ni*16 + l16;
      f32x4 acc = {0.f,0.f,0.f,0.f};
      #pragma unroll
      for (int ks=0; ks<2; ks++){
        s16x8 bh = *(const s16x8*)(w2h + (size_t)o*64 + ks*32 + quad*8);
        s16x8 bl = *(const s16x8*)(w2l + (size_t)o*64 + ks*32 + quad*8);
        mfma16(acc, ah[ks], bh);
        mfma16(acc, ah[ks], bl);
        mfma16(acc, al[ks], bh);
      }
      mfma_guard(acc);
      float vmax = fmaxf(fmaxf(acc[0],acc[1]), fmaxf(acc[2],acc[3]));
      vmax = fmaxf(vmax, __shfl_xor(vmax,16));
      vmax = fmaxf(vmax, __shfl_xor(vmax,32));
      if (quad==0) P1g[o] = vmax + b2[o];
    }
  }
}

// ---------------- SA2 (all branches) -> X3 bf16 hi/lo ----------------
template<int K>
DEVI void sa2_body(int br, int g2, short* Xb, short* Hb, float* ctr, int* idxs){
  constexpr int MT = K/16;
  const int b = g2 >> 7;
  const int t = threadIdx.x;
  const int wave = t >> 6, lane = t & 63, quad = lane >> 4, l16 = lane & 15;
  const int* kn2 = (const int*)(g_ws + OFF_KNN2) + (size_t)g2*48;
  if (t < K) idxs[t] = kn2[t] & (S1-1);
  if (t < 3) ctr[t] = g_ws[(t==0?OFF_NX2X:(t==1?OFF_NX2Y:OFF_NX2Z)) + g2];
  __syncthreads();
  const float* p1b = g_ws + OFF_P1 + (size_t)br*16384*128;
  for (int e=t; e<K*168; e+=256){
    int k = e/168, j = e%168;
    int idx = idxs[k];
    float v;
    if (j < 3){
      const float* A = (j==0)? g_ws+OFF_NX1X : (j==1)? g_ws+OFF_NX1Y : g_ws+OFF_NX1Z;
      v = A[(size_t)b*S1 + idx] - ctr[j];
    } else if (j < 131){
      v = p1b[((size_t)b*S1 + idx)*128 + (j-3)];
    } else v = 0.f;
    Xb[e] = (short)f2bf(v);
  }
  __syncthreads();
  {
    const short* w1bf = (const short*)(g_ws + OFF_W1BF) + (size_t)br*128*160;
    const float* b1 = g_ws + B1B + br*128;
    for (int ni = wave; ni < 8; ni += 4){
      int h = ni*16 + l16;
      s16x8 bfr[5];
      #pragma unroll
      for (int ks=0;ks<5;ks++) bfr[ks] = *(const s16x8*)(w1bf + (size_t)h*160 + ks*32 + quad*8);
      float bias = b1[h];
      #pragma unroll
      for (int m=0; m<MT; m++){
        f32x4 acc = {0.f,0.f,0.f,0.f};
        #pragma unroll
        for (int ks=0;ks<5;ks++){
          s16x8 a = *(const s16x8*)(&Xb[(m*16 + l16)*168 + ks*32 + quad*8]);
          mfma16(acc, a, bfr[ks]);
        }
        mfma_guard(acc);
        #pragma unroll
        for (int r=0;r<4;r++){
          int row = m*16 + quad*4 + r;
          float hv = fmaxf(acc[r] + bias, 0.f);
          Hb[row*136 + ni*16 + l16] = (short)f2bf(hv);
        }
      }
    }
  }
  __syncthreads();
  {
    const short* w2bf = (const short*)(g_ws + OFF_W2BF) + (size_t)br*256*128;
    const float* b2 = g_ws + B2B + br*256;
    unsigned short* xh = (unsigned short*)(g_ws + OFF_X3BH);
    unsigned short* xlo = (unsigned short*)(g_ws + OFF_X3BL);
    size_t row = (size_t)(br*4096 + g2)*288;
    for (int ni = wave; ni < 16; ni += 4){
      int o = ni*16 + l16;
      s16x8 bfr[4];
      #pragma unroll
      for (int ks=0;ks<4;ks++) bfr[ks] = *(const s16x8*)(w2bf + (size_t)o*128 + ks*32 + quad*8);
      float vmax = -3.4e38f;
      #pragma unroll
      for (int m=0; m<MT; m++){
        f32x4 acc = {0.f,0.f,0.f,0.f};
        #pragma unroll
        for (int ks=0;ks<4;ks++){
          s16x8 a = *(const s16x8*)(&Hb[(m*16 + l16)*136 + ks*32 + quad*8]);
          mfma16(acc, a, bfr[ks]);
        }
        mfma_guard(acc);
        #pragma unroll
        for (int r=0;r<4;r++) vmax = fmaxf(vmax, acc[r]);
      }
      vmax = fmaxf(vmax, __shfl_xor(vmax, 16));
      vmax = fmaxf(vmax, __shfl_xor(vmax, 32));
      if (quad == 0){
        float hv = vmax + b2[o];
        unsigned short hi = f2bf(hv);
        xh[row + 3 + o] = hi;
        xlo[row + 3 + o] = f2bf(hv - bfbits2f(hi));
      }
    }
    if (t < 3){
      float cv = ctr[t];
      unsigned short hi = f2bf(cv);
      xh[row + t] = hi; xlo[row + t] = f2bf(cv - bfbits2f(hi));
    }
    if (t >= 3 && t < 32){ xh[row + 256 + t] = 0; xlo[row + 256 + t] = 0; }
  }
}

__global__ __launch_bounds__(256) void sa2_all_kernel(){
  __shared__ __align__(16) short Xb[48*168];
  __shared__ __align__(16) short Hb[48*136];
  __shared__ float ctr[3];
  __shared__ int idxs[48];
  int br = blockIdx.x >> 12;
  int g2 = blockIdx.x & 4095;
  if (br == 0)      sa2_body<16>(0, g2, Xb, Hb, ctr, idxs);
  else if (br == 1) sa2_body<32>(1, g2, Xb, Hb, ctr, idxs);
  else              sa2_body<48>(2, g2, Xb, Hb, ctr, idxs);
}

// ---------------- SA3 layer1 via MFMA (hi/lo): 288 -> 512 relu ----------------
__global__ __launch_bounds__(256) void sa3l1_mfma_kernel(){
  const int br = blockIdx.y; const int r0 = blockIdx.x*32;
  const int t = threadIdx.x;
  const int wave = t >> 6, lane = t & 63, quad = lane >> 4, l16 = lane & 15;
  const short* xh = (const short*)(g_ws + OFF_X3BH) + (size_t)(br*4096 + r0)*288;
  const short* xl = (const short*)(g_ws + OFF_X3BL) + (size_t)(br*4096 + r0)*288;
  const short* wh = (const short*)(g_ws + OFF_W1CBH) + (size_t)br*512*288;
  const short* wl = (const short*)(g_ws + OFF_W1CBL) + (size_t)br*512*288;
  const float* bias = g_ws + B1C + br*512;
  unsigned short* hh = (unsigned short*)(g_ws + OFF_H3BH) + (size_t)(br*4096 + r0)*512;
  unsigned short* hl = (unsigned short*)(g_ws + OFF_H3BL) + (size_t)(br*4096 + r0)*512;
  f32x4 acc[2][8];
  #pragma unroll
  for (int m=0;m<2;m++)
    #pragma unroll
    for (int ni=0;ni<8;ni++) acc[m][ni] = (f32x4){0.f,0.f,0.f,0.f};
  for (int ks=0; ks<9; ks++){
    s16x8 ah[2], al[2];
    #pragma unroll
    for (int m=0;m<2;m++){
      ah[m] = *(const s16x8*)(xh + (size_t)(m*16+l16)*288 + ks*32 + quad*8);
      al[m] = *(const s16x8*)(xl + (size_t)(m*16+l16)*288 + ks*32 + quad*8);
    }
    #pragma unroll
    for (int ni=0;ni<8;ni++){
      int n = wave*128 + ni*16 + l16;
      s16x8 bh = *(const s16x8*)(wh + (size_t)n*288 + ks*32 + quad*8);
      s16x8 bl = *(const s16x8*)(wl + (size_t)n*288 + ks*32 + quad*8);
      #pragma unroll
      for (int m=0;m<2;m++){
        mfma16(acc[m][ni], ah[m], bh);
        mfma16(acc[m][ni], ah[m], bl);
        mfma16(acc[m][ni], al[m], bh);
      }
    }
  }
  mfma_guard(acc[0][0]);
  #pragma unroll
  for (int m=0;m<2;m++){
    #pragma unroll
    for (int ni=0;ni<8;ni++){
      int col = wave*128 + ni*16 + l16;
      float bs = bias[col];
      #pragma unroll
      for (int r=0;r<4;r++){
        int row = m*16 + quad*4 + r;
        float hv = fmaxf(acc[m][ni][r] + bs, 0.f);
        unsigned short hi = f2bf(hv);
        hh[(size_t)row*512 + col] = hi;
        hl[(size_t)row*512 + col] = f2bf(hv - bfbits2f(hi));
      }
    }
  }
}

// ---------------- SA3 layer2 via MFMA (hi/lo): 512 -> 512, partial max ----------------
__global__ __launch_bounds__(256) void sa3l2_mfma_kernel(){
  const int br = blockIdx.y; const int b = blockIdx.x>>2; const int part = blockIdx.x&3;
  const int t = threadIdx.x;
  const int wave = t >> 6, lane = t & 63, quad = lane >> 4, l16 = lane & 15;
  const int row0 = b*128 + part*32;
  const short* ahp = (const short*)(g_ws + OFF_H3BH) + (size_t)(br*4096 + row0)*512;
  const short* alp = (const short*)(g_ws + OFF_H3BL) + (size_t)(br*4096 + row0)*512;
  const short* wh = (const short*)(g_ws + OFF_W2CBH) + (size_t)br*512*512;
  const short* wl = (const short*)(g_ws + OFF_W2CBL) + (size_t)br*512*512;
  f32x4 acc[2][8];
  #pragma unroll
  for (int m=0;m<2;m++)
    #pragma unroll
    for (int ni=0;ni<8;ni++) acc[m][ni] = (f32x4){0.f,0.f,0.f,0.f};
  for (int ks=0; ks<16; ks++){
    s16x8 ah[2], al[2];
    #pragma unroll
    for (int m=0;m<2;m++){
      ah[m] = *(const s16x8*)(ahp + (size_t)(m*16+l16)*512 + ks*32 + quad*8);
      al[m] = *(const s16x8*)(alp + (size_t)(m*16+l16)*512 + ks*32 + quad*8);
    }
    #pragma unroll
    for (int ni=0;ni<8;ni++){
      int n = wave*128 + ni*16 + l16;
      s16x8 bh = *(const s16x8*)(wh + (size_t)n*512 + ks*32 + quad*8);
      s16x8 bl = *(const s16x8*)(wl + (size_t)n*512 + ks*32 + quad*8);
      #pragma unroll
      for (int m=0;m<2;m++){
        mfma16(acc[m][ni], ah[m], bh);
        mfma16(acc[m][ni], ah[m], bl);
        mfma16(acc[m][ni], al[m], bh);
      }
    }
  }
  mfma_guard(acc[0][0]);
  #pragma unroll
  for (int ni=0;ni<8;ni++){
    float vmax = -3.4e38f;
    #pragma unroll
    for (int m=0;m<2;m++)
      #pragma unroll
      for (int r=0;r<4;r++) vmax = fmaxf(vmax, acc[m][ni][r]);
    vmax = fmaxf(vmax, __shfl_xor(vmax, 16));
    vmax = fmaxf(vmax, __shfl_xor(vmax, 32));
    if (quad == 0){
      int col = wave*128 + ni*16 + l16;
      g_ws[OFF_O3P + (((size_t)br*BB + b)*4 + part)*512 + col] = vmax;
    }
  }
}

// ---------------- FC head + combine fused (f32 out) ----------------
__global__ __launch_bounds__(256) void fc_kernel(float* __restrict__ out, int out_size){
  int br = blockIdx.x >> 5; int b = blockIdx.x & 31; int t = threadIdx.x;
  __shared__ float xin[512]; __shared__ float x1s[256];
  const float* o3p = g_ws + OFF_O3P + (((size_t)br*BB + b)*4)*512;
  const float* b2c = g_ws + B2C + br*512;
  #pragma unroll
  for (int k=0;k<2;k++){
    int o = t + k*256;
    float m = fmaxf(fmaxf(o3p[o], o3p[512+o]), fmaxf(o3p[1024+o], o3p[1536+o]));
    m += b2c[o];
    xin[o] = m;
    int oi = 3*BB*128 + ((br*BB + b)*512) + o;
    if (oi < out_size) out[oi] = m;
  }
  __syncthreads();
  const float s = (float)(1.0 / sqrt(1.0 + 1e-5));
  {
    const float4* wp = (const float4*)(g_ws + FW1 + ((size_t)br*256 + t)*512);
    const float4* xp = (const float4*)xin;
    float acc = 0.f;
    #pragma unroll 8
    for (int q=0;q<128;q++){ float4 w4=wp[q], x4=xp[q]; acc += w4.x*x4.x + w4.y*x4.y + w4.z*x4.z + w4.w*x4.w; }
    acc = (acc + g_ws[FB1 + br*256+t]) * s;
    acc = g_ws[FG1+br*256+t]*acc + g_ws[FBE1+br*256+t];
    x1s[t] = fmaxf(acc, 0.f);
  }
  __syncthreads();
  if (t < 128){
    const float4* wp = (const float4*)(g_ws + FW2 + ((size_t)br*128 + t)*256);
    const float4* xp = (const float4*)x1s;
    float acc=0.f;
    #pragma unroll 8
    for (int q=0;q<64;q++){ float4 w4=wp[q], x4=xp[q]; acc += w4.x*x4.x + w4.y*x4.y + w4.z*x4.z + w4.w*x4.w; }
    acc = (acc + g_ws[FB2+br*128+t])*s;
    acc = g_ws[FG2+br*128+t]*acc + g_ws[FBE2+br*128+t];
    int oi = ((size_t)br*BB + b)*128 + t;
    if (oi < out_size) out[oi] = fmaxf(acc,0.f);
  }
}

// ---------------- launch (R14: revert fps1 to R12-proven 128-thread version) ----------------
extern "C" void kernel_launch(void* const* d_in, const int* in_sizes, int n_in,
                              void* d_out, int out_size, void* d_ws, size_t ws_size,
                              hipStream_t stream) {
  (void)d_ws; (void)ws_size;
  if (n_in < 21) return;
  if (in_sizes[0] != BB*3*NN) return;
  float* out = (float*)d_out;

  ParamPtrs pp;
  for (int i=0;i<20;i++) pp.p[i] = d_in[i+1];

  init_detect_kernel<<<1,256,0,stream>>>(d_in[0]);
  cvtprep_kernel<<<768,256,0,stream>>>(pp, d_in[0], 0);
  scan_check_kernel<<<256,256,0,stream>>>();
  resolve_flip_kernel<<<1,64,0,stream>>>();
  cvtprep_kernel<<<768,256,0,stream>>>(pp, d_in[0], 1);   // gated on g_flip

  fps1_cvt_kernel<<<32+512,128,0,stream>>>();             // fps1 (32 blk) + cvt_bf16 (512 blk)
  fps2_knn1_kernel<<<32+4096,256,0,stream>>>();
  knn2_sa1_kernel<<<1024+3072,256,0,stream>>>();
  sa2_all_kernel<<<3*4096,256,0,stream>>>();

  sa3l1_mfma_kernel<<<dim3(128,3),256,0,stream>>>();
  sa3l2_mfma_kernel<<<dim3(128,3),256,0,stream>>>();
  fc_kernel<<<96,256,0,stream>>>(out, out_size);          // combine fused in
}